// Round 8
// baseline (1923.186 us; speedup 1.0000x reference)
//
#include <hip/hip_runtime.h>
#include <math.h>

#define BATCH 512
#define TM1   31
#define DIMD  256

typedef _Float16 f16;
typedef _Float16 half8 __attribute__((ext_vector_type(8)));
typedef float floatx16 __attribute__((ext_vector_type(16)));

__device__ __forceinline__ float sigmf(float x) { return 1.f / (1.f + __expf(-x)); }

__device__ __forceinline__ float tanh_fast(float x) {
    float ax = fabsf(x);
    float t  = __expf(-2.f * ax);
    float r  = (1.f - t) / (1.f + t);
    return copysignf(r, x);
}

__device__ __forceinline__ void split16(float x, f16* hi, f16* lo) {
    f16 h = (f16)x;
    *hi = h;
    *lo = (f16)(x - (float)h);
}

__device__ __forceinline__ float blockReduceSum256(float v, float* sred) {
#pragma unroll
    for (int m = 32; m > 0; m >>= 1) v += __shfl_xor(v, m);
    __syncthreads();
    if ((threadIdx.x & 63) == 0) sred[threadIdx.x >> 6] = v;
    __syncthreads();
    return sred[0] + sred[1] + sred[2] + sred[3];
}

__device__ __forceinline__ float blockReduceMax256(float v, float* sred) {
#pragma unroll
    for (int m = 32; m > 0; m >>= 1) v = fmaxf(v, __shfl_xor(v, m));
    __syncthreads();
    if ((threadIdx.x & 63) == 0) sred[threadIdx.x >> 6] = v;
    __syncthreads();
    return fmaxf(fmaxf(sred[0], sred[1]), fmaxf(sred[2], sred[3]));
}

// ---------------------------------------------------------------------------
// prep + t2s fused: block b computes t2s for batch b; all blocks grid-stride
// the weight hi/lo splits.
// ---------------------------------------------------------------------------
__global__ __launch_bounds__(256) void prep_t2s_kernel(
    const float* __restrict__ inputs,
    const float* __restrict__ eWih, const float* __restrict__ eWhh,
    const float* __restrict__ ebih, const float* __restrict__ ebhh,
    const float* __restrict__ dW1,  const float* __restrict__ dWhh,
    const float* __restrict__ dbih, const float* __restrict__ dbhh,
    const float* __restrict__ Wd,   const float* __restrict__ bd,
    f16* __restrict__ eWhi, f16* __restrict__ eWlo,
    f16* __restrict__ dWchi, f16* __restrict__ dWclo,
    f16* __restrict__ Vwhi, f16* __restrict__ Vwlo,
    float* __restrict__ ebcomb, float* __restrict__ dbias,
    float* __restrict__ t2s)
{
    __shared__ float sX[TM1 * DIMD];
    __shared__ float sWd[TM1 * TM1];
    int b = blockIdx.x, tid = threadIdx.x;
    int idx = b * 256 + tid;
    const int stride = 512 * 256;

    for (int i = tid; i < TM1 * DIMD; i += 256) {
        int tt = i >> 8, d = i & 255;
        sX[i] = inputs[((size_t)b * TM1 + tt) * 257 + 1 + d];
    }
    for (int i = tid; i < TM1 * TM1; i += 256) sWd[i] = Wd[i];
    __syncthreads();
    int d = tid;
    for (int s = 0; s < TM1; s++) {
        float acc = bd[s];
        for (int tt = 0; tt < TM1; tt++) acc += sX[tt * DIMD + d] * sWd[s * TM1 + tt];
        t2s[((size_t)b * TM1 + s) * DIMD + d] = acc;
    }

    for (int i = idx; i < 2048 * 768; i += stride) {
        int n = i / 768, k = i - n * 768;
        float v = (k < 256) ? eWih[n * 256 + k] : eWhh[n * 512 + (k - 256)];
        split16(v, &eWhi[i], &eWlo[i]);
    }
    for (int i = idx; i < 2560 * 1024; i += stride) {
        int n = i >> 10, k = i & 1023;
        float v;
        if (n < 512)      v = dW1[n * 1536 + k];
        else if (k < 512) v = dWhh[(n - 512) * 512 + k];
        else              v = 0.f;
        split16(v, &dWchi[i], &dWclo[i]);
    }
    for (int i = idx; i < 512 * 512; i += stride) {
        int n = i >> 9, k = i & 511;
        split16(dW1[n * 1536 + 1024 + k], &Vwhi[i], &Vwlo[i]);
    }
    for (int i = idx; i < 2048; i += stride) ebcomb[i] = ebih[i] + ebhh[i];
    for (int i = idx; i < 2560; i += stride)
        dbias[i] = (i < 512) ? 0.f : (dbih[i - 512] + dbhh[i - 512]);
}

// ---------------------------------------------------------------------------
// Step GEMM (fp16x2, split-K): C_ks[m,n] = sum_{k in slice} A[m,k]*(Whi+Wlo)[n,k]
// A is in FRAGMENT layout: A[rb][g][r6][8], rb=row/64, g=k/8, r6=row%64 —
// MFMA A-operands load directly from global as two contiguous 512B segments
// per wave (no LDS staging for A). W hi/lo staged in XOR-swizzled LDS.
// grid 1-D: n=bid%NT, m=(bid/NT)%MT, ks=bid/(NT*MT). NT%8==0 -> n-tile XCD-
// pinned (weight slice L2-resident across 31 step dispatches).
// Kfull = (n0>=nsplit) ? 512 : K; slice = Kfull/KS (%64==0). Bias on ks==0.
// ---------------------------------------------------------------------------
__global__ __launch_bounds__(256) void gemm_step(
    const f16* __restrict__ Af, int Kg,
    const f16* __restrict__ Whi, const f16* __restrict__ Wlo, int ldw,
    const float* __restrict__ bias, float* __restrict__ C, int ldc,
    long long Cstride, int K, int nsplit, int NT, int MT, int KS)
{
    __shared__ f16 sWh[64 * 64];
    __shared__ f16 sWl[64 * 64];
    int tid = threadIdx.x, bid = blockIdx.x;
    int nbase = bid % NT;
    int mt = (bid / NT) % MT;
    int ks = bid / (NT * MT);
    int lane = tid & 63, wid = tid >> 6;
    int wm = wid >> 1, wn = wid & 1;
    int rl = lane & 31, kq = lane >> 5;

    int sr = tid >> 2;
    int g0 = (tid & 3) * 2;
    int s0 = sr * 64 + ((g0 ^ (sr & 7)) * 8);
    int s1 = sr * 64 + (((g0 + 1) ^ (sr & 7)) * 8);
    int wrow = (wn * 32 + rl) * 64;
    int sw = (rl & 7);
    int r6 = wm * 32 + rl;

    const f16* pA = Af + (size_t)mt * Kg * 512 + r6 * 8 + kq * 512;

    int n0 = nbase * 64;
    int Kfull = (n0 >= nsplit) ? 512 : K;
    int ksz = Kfull / KS;
    int kbeg = ks * ksz, kend = kbeg + ksz;
    const f16* pWh = Whi + (size_t)(n0 + sr) * ldw + g0 * 8;
    const f16* pWl = Wlo + (size_t)(n0 + sr) * ldw + g0 * 8;

    float4 rWh0 = *(const float4*)(pWh + kbeg);
    float4 rWh1 = *(const float4*)(pWh + kbeg + 8);
    float4 rWl0 = *(const float4*)(pWl + kbeg);
    float4 rWl1 = *(const float4*)(pWl + kbeg + 8);

    floatx16 acc = {};

    for (int k0 = kbeg; k0 < kend; k0 += 64) {
        // A fragments for this chunk: issue early (independent of LDS)
        const f16* pAk = pA + (size_t)k0 * 64;
        half8 a0 = *(const half8*)(pAk);
        half8 a1 = *(const half8*)(pAk + 1024);
        half8 a2 = *(const half8*)(pAk + 2048);
        half8 a3 = *(const half8*)(pAk + 3072);
        __syncthreads();
        *(float4*)&sWh[s0] = rWh0; *(float4*)&sWh[s1] = rWh1;
        *(float4*)&sWl[s0] = rWl0; *(float4*)&sWl[s1] = rWl1;
        __syncthreads();
        int kn = k0 + 64;
        if (kn < kend) {
            rWh0 = *(const float4*)(pWh + kn); rWh1 = *(const float4*)(pWh + kn + 8);
            rWl0 = *(const float4*)(pWl + kn); rWl1 = *(const float4*)(pWl + kn + 8);
        }
        int off;
        off = ((0 + kq) ^ sw) * 8;
        acc = __builtin_amdgcn_mfma_f32_32x32x16_f16(a0, *(const half8*)&sWh[wrow + off], acc, 0, 0, 0);
        acc = __builtin_amdgcn_mfma_f32_32x32x16_f16(a0, *(const half8*)&sWl[wrow + off], acc, 0, 0, 0);
        off = ((2 + kq) ^ sw) * 8;
        acc = __builtin_amdgcn_mfma_f32_32x32x16_f16(a1, *(const half8*)&sWh[wrow + off], acc, 0, 0, 0);
        acc = __builtin_amdgcn_mfma_f32_32x32x16_f16(a1, *(const half8*)&sWl[wrow + off], acc, 0, 0, 0);
        off = ((4 + kq) ^ sw) * 8;
        acc = __builtin_amdgcn_mfma_f32_32x32x16_f16(a2, *(const half8*)&sWh[wrow + off], acc, 0, 0, 0);
        acc = __builtin_amdgcn_mfma_f32_32x32x16_f16(a2, *(const half8*)&sWl[wrow + off], acc, 0, 0, 0);
        off = ((6 + kq) ^ sw) * 8;
        acc = __builtin_amdgcn_mfma_f32_32x32x16_f16(a3, *(const half8*)&sWh[wrow + off], acc, 0, 0, 0);
        acc = __builtin_amdgcn_mfma_f32_32x32x16_f16(a3, *(const half8*)&sWl[wrow + off], acc, 0, 0, 0);
    }

    int col = n0 + wn * 32 + rl;
    float bv = (ks == 0) ? bias[col] : 0.f;
    float* Cp = C + (size_t)ks * Cstride;
#pragma unroll
    for (int rr = 0; rr < 16; ++rr) {
        int row = mt * 64 + wm * 32 + (rr & 3) + 8 * (rr >> 2) + 4 * kq;
        Cp[(size_t)row * ldc + col] = acc[rr] + bv;
    }
}

// ---------------------------------------------------------------------------
// V GEMM (R7-validated path): A row-major, LDS-staged; NREP sweeps n-tiles
// reusing the A tile. fp16x2.
// ---------------------------------------------------------------------------
__global__ __launch_bounds__(256) void gemm_v(
    const f16* __restrict__ Ahi, int lda,
    const f16* __restrict__ Whi, const f16* __restrict__ Wlo, int ldw,
    const float* __restrict__ bias, float* __restrict__ C, int ldc,
    int K, int NT, int MT, int NREP)
{
    __shared__ f16 sAh[64 * 64];
    __shared__ f16 sWh[64 * 64];
    __shared__ f16 sWl[64 * 64];
    int tid = threadIdx.x, bid = blockIdx.x;
    int nbase = bid % NT;
    int m0 = ((bid / NT) % MT) * 64;
    int lane = tid & 63, wid = tid >> 6;
    int wm = wid >> 1, wn = wid & 1;
    int rl = lane & 31, kq = lane >> 5;

    int sr = tid >> 2;
    int g0 = (tid & 3) * 2;
    int s0 = sr * 64 + ((g0 ^ (sr & 7)) * 8);
    int s1 = sr * 64 + (((g0 + 1) ^ (sr & 7)) * 8);
    int arow = (wm * 32 + rl) * 64;
    int wrow = (wn * 32 + rl) * 64;
    int sw = (rl & 7);

    const f16* pAh = Ahi + (size_t)(m0 + sr) * lda + g0 * 8;

    for (int r = 0; r < NREP; ++r) {
        int n0 = (nbase + r * NT) * 64;
        const f16* pWh = Whi + (size_t)(n0 + sr) * ldw + g0 * 8;
        const f16* pWl = Wlo + (size_t)(n0 + sr) * ldw + g0 * 8;

        float4 rAh0 = *(const float4*)(pAh);
        float4 rAh1 = *(const float4*)(pAh + 8);
        float4 rWh0 = *(const float4*)(pWh);
        float4 rWh1 = *(const float4*)(pWh + 8);
        float4 rWl0 = *(const float4*)(pWl);
        float4 rWl1 = *(const float4*)(pWl + 8);

        floatx16 acc = {};

        for (int k0 = 0; k0 < K; k0 += 64) {
            __syncthreads();
            *(float4*)&sAh[s0] = rAh0; *(float4*)&sAh[s1] = rAh1;
            *(float4*)&sWh[s0] = rWh0; *(float4*)&sWh[s1] = rWh1;
            *(float4*)&sWl[s0] = rWl0; *(float4*)&sWl[s1] = rWl1;
            __syncthreads();
            int kn = k0 + 64;
            if (kn < K) {
                rAh0 = *(const float4*)(pAh + kn); rAh1 = *(const float4*)(pAh + kn + 8);
                rWh0 = *(const float4*)(pWh + kn); rWh1 = *(const float4*)(pWh + kn + 8);
                rWl0 = *(const float4*)(pWl + kn); rWl1 = *(const float4*)(pWl + kn + 8);
            }
#pragma unroll
            for (int kk = 0; kk < 64; kk += 16) {
                int lg = (kk >> 3) + kq;
                int off = ((lg ^ sw) * 8);
                half8 ah = *(const half8*)&sAh[arow + off];
                half8 wh = *(const half8*)&sWh[wrow + off];
                half8 wl = *(const half8*)&sWl[wrow + off];
                acc = __builtin_amdgcn_mfma_f32_32x32x16_f16(ah, wh, acc, 0, 0, 0);
                acc = __builtin_amdgcn_mfma_f32_32x32x16_f16(ah, wl, acc, 0, 0, 0);
            }
        }

        int col = n0 + wn * 32 + rl;
        float bv = bias[col];
#pragma unroll
        for (int rr = 0; rr < 16; ++rr) {
            int row = m0 + wm * 32 + (rr & 3) + 8 * (rr >> 2) + 4 * kq;
            C[(size_t)row * ldc + col] = acc[rr] + bv;
        }
    }
}

// ---------------------------------------------------------------------------
// Encoder step: 512 blocks, one batch per block. Finalize LSTM t-1 from 4
// split-K g-slices, attention t, write A in fragment layout (Kg=96).
// ---------------------------------------------------------------------------
__global__ __launch_bounds__(256) void enc_step_kernel(
    const float* __restrict__ inputs, const float* __restrict__ t2s,
    const float* __restrict__ Wc, const float* __restrict__ bc,
    const float* __restrict__ Wa, const float* __restrict__ ba,
    const float* __restrict__ g, long long gstride,
    float* __restrict__ hc,
    f16* __restrict__ Af, f16* __restrict__ enchi,
    float* __restrict__ hc_dec, f16* __restrict__ hdf,
    int t) {
    __shared__ float sh_hc[1024];
    __shared__ float sh_w[256];
    __shared__ float t1s[32];
    __shared__ float sred[4];
    int b = blockIdx.x, tid = threadIdx.x;

    if (t > 0) {
        for (int e = tid; e < 512; e += 256) {
            const float* gp = g + (size_t)b * 2048 + e;
            float gi = 0.f, gf = 0.f, gg = 0.f, go = 0.f;
#pragma unroll
            for (int s = 0; s < 4; s++) {
                const float* q = gp + s * gstride;
                gi += q[0]; gf += q[512]; gg += q[1024]; go += q[1536];
            }
            float cp = hc[b * 1024 + 512 + e];
            float c2 = sigmf(gf) * cp + sigmf(gi) * tanh_fast(gg);
            float h2 = sigmf(go) * tanh_fast(c2);
            hc[b * 1024 + e] = h2;
            hc[b * 1024 + 512 + e] = c2;
            sh_hc[e] = h2;
            sh_hc[512 + e] = c2;
            enchi[((size_t)b * TM1 + (t - 1)) * 512 + e] = (f16)h2;
        }
    } else {
        for (int j = tid; j < 1024; j += 256) { sh_hc[j] = 0.f; hc[b * 1024 + j] = 0.f; }
    }
    if (t == TM1) {
        for (int j = tid; j < 1024; j += 256) {
            hc_dec[b * 1024 + j] = 0.f;
            hdf[b * 1024 + j] = (f16)0.f;
        }
        return;
    }
    __syncthreads();

    if (tid < 248) {
        int s = tid >> 3, l8 = tid & 7;
        const float* wrow = Wc + s * 1024;
        float p = 0.f;
        for (int j = l8 * 4; j < 1024; j += 32) {
            float4 w4 = *(const float4*)(wrow + j);
            float4 h4 = *(const float4*)(&sh_hc[j]);
            p += w4.x * h4.x + w4.y * h4.y + w4.z * h4.z + w4.w * h4.w;
        }
        p += __shfl_xor(p, 1); p += __shfl_xor(p, 2); p += __shfl_xor(p, 4);
        if (l8 == 0) t1s[s] = p + bc[s];
    }
    __syncthreads();

    int d = tid;
    float sc = ba[0];
    const float* t2p = t2s + ((size_t)b * TM1) * DIMD + d;
    for (int s = 0; s < TM1; s++) sc += tanh_fast(t1s[s] + t2p[s * DIMD]) * Wa[s];
    float mx = blockReduceMax256(sc, sred);
    float ex = __expf(sc - mx);
    float sm = blockReduceSum256(ex, sred);
    sh_w[d] = (ex / sm) * inputs[((size_t)b * TM1 + t) * 257 + 1 + d];
    __syncthreads();

    // A = [w(256) | h(512)] in fragment layout: Af[(rb*96+g)*64 + r6][8]
    if (tid < 96) {
        int gidx = tid;
        f16 tmp[8];
#pragma unroll
        for (int e = 0; e < 8; e++) {
            int k = gidx * 8 + e;
            float v = (k < 256) ? sh_w[k] : sh_hc[k - 256];
            tmp[e] = (f16)v;
        }
        *(half8*)(Af + (((size_t)(b >> 6) * 96 + gidx) * 64 + (b & 63)) * 8) = *(half8*)tmp;
    }
}

// ---------------------------------------------------------------------------
// Decoder step: attention + ctx + y_tilde + LSTM pointwise from 4 gu-slices;
// writes [h|c] in fragment layout (Kg=128). Last step fuses final FC.
// ---------------------------------------------------------------------------
__global__ __launch_bounds__(256) void dec_step_kernel(
    const float* __restrict__ inputs, const float* __restrict__ V,
    const float* __restrict__ W2, const float* __restrict__ b2,
    const f16* __restrict__ enchi,
    const float* __restrict__ fcW, const float* __restrict__ fcb,
    const float* __restrict__ Wih,
    const float* __restrict__ gu, long long ustride,
    float* __restrict__ hc, f16* __restrict__ hdf,
    const float* __restrict__ fcfW, const float* __restrict__ fcfb,
    float* __restrict__ out, int t) {
    __shared__ float su[512];
    __shared__ float sw2[512];
    __shared__ float shc[1024];
    __shared__ float s_att[TM1];
    __shared__ float sred[4];
    int b = blockIdx.x, tid = threadIdx.x;
    const bool last = (t == TM1 - 1);
    for (int e = tid; e < 512; e += 256) {
        const float* q = gu + (size_t)b * 2560 + e;
        su[e] = q[0] + q[ustride] + q[2 * ustride] + q[3 * ustride];
        sw2[e] = W2[e];
    }
    __syncthreads();
    if (tid < 248) {
        int tp = tid >> 3, l8 = tid & 7;
        const float* vrow = V + ((size_t)b * TM1 + tp) * 512;
        float p = 0.f;
        for (int j = l8 * 4; j < 512; j += 32) {
            float4 v4 = *(const float4*)(vrow + j);
            p += tanh_fast(su[j + 0] + v4.x) * sw2[j + 0]
               + tanh_fast(su[j + 1] + v4.y) * sw2[j + 1]
               + tanh_fast(su[j + 2] + v4.z) * sw2[j + 2]
               + tanh_fast(su[j + 3] + v4.w) * sw2[j + 3];
        }
        p += __shfl_xor(p, 1); p += __shfl_xor(p, 2); p += __shfl_xor(p, 4);
        if (l8 == 0) s_att[tp] = p + b2[0];
    }
    __syncthreads();
    if (tid < 64) {
        float v = (tid < TM1) ? s_att[tid] : -3.4e38f;
        float m = v;
#pragma unroll
        for (int k = 32; k > 0; k >>= 1) m = fmaxf(m, __shfl_xor(m, k));
        float e = (tid < TM1) ? __expf(v - m) : 0.f;
        float s = e;
#pragma unroll
        for (int k = 32; k > 0; k >>= 1) s += __shfl_xor(s, k);
        if (tid < TM1) s_att[tid] = e / s;
    }
    __syncthreads();

    float part = 0.f;
    float pctx = 0.f;
#pragma unroll
    for (int r = 0; r < 2; r++) {
        int e = tid + r * 256;
        float cx = 0.f;
        const f16* eh = enchi + (size_t)b * TM1 * 512 + e;
        for (int tp = 0; tp < TM1; tp++)
            cx += s_att[tp] * (float)eh[tp * 512];
        part += cx * fcW[e];
        if (last) pctx += cx * fcfW[512 + e];
    }
    float y = inputs[((size_t)b * TM1 + t) * 257];
    float ysum = blockReduceSum256(part, sred);
    float y_til = ysum + y * fcW[512] + fcb[0];

    float ph = 0.f;
    for (int e = tid; e < 512; e += 256) {
        const float* q = gu + (size_t)b * 2560 + e;
        float gi = q[512]  + q[ustride + 512]  + q[2 * ustride + 512]  + q[3 * ustride + 512]  + y_til * Wih[e];
        float gf = q[1024] + q[ustride + 1024] + q[2 * ustride + 1024] + q[3 * ustride + 1024] + y_til * Wih[512 + e];
        float gg = q[1536] + q[ustride + 1536] + q[2 * ustride + 1536] + q[3 * ustride + 1536] + y_til * Wih[1024 + e];
        float go = q[2048] + q[ustride + 2048] + q[2 * ustride + 2048] + q[3 * ustride + 2048] + y_til * Wih[1536 + e];
        float cp = hc[b * 1024 + 512 + e];
        float c2 = sigmf(gf) * cp + sigmf(gi) * tanh_fast(gg);
        float h2 = sigmf(go) * tanh_fast(c2);
        if (!last) {
            hc[b * 1024 + e] = h2;
            hc[b * 1024 + 512 + e] = c2;
            shc[e] = h2;
            shc[512 + e] = c2;
        } else {
            ph += h2 * fcfW[e];
        }
    }
    if (last) {
        float s = blockReduceSum256(ph + pctx, sred);
        if (tid == 0) out[b] = s + fcfb[0];
        return;
    }
    __syncthreads();
    // [h|c] fragment layout: hdf[(rb*128+g)*64 + r6][8]
    if (tid < 128) {
        int gidx = tid;
        f16 tmp[8];
#pragma unroll
        for (int e = 0; e < 8; e++) tmp[e] = (f16)shc[gidx * 8 + e];
        *(half8*)(hdf + (((size_t)(b >> 6) * 128 + gidx) * 64 + (b & 63)) * 8) = *(half8*)tmp;
    }
}

extern "C" void kernel_launch(void* const* d_in, const int* in_sizes, int n_in,
                              void* d_out, int out_size, void* d_ws, size_t ws_size,
                              hipStream_t stream) {
    const float* inputs  = (const float*)d_in[0];
    const float* eWih    = (const float*)d_in[1];
    const float* eWhh    = (const float*)d_in[2];
    const float* ebih    = (const float*)d_in[3];
    const float* ebhh    = (const float*)d_in[4];
    const float* eWc     = (const float*)d_in[5];
    const float* ebc     = (const float*)d_in[6];
    const float* eWd     = (const float*)d_in[7];
    const float* ebd     = (const float*)d_in[8];
    const float* eWa     = (const float*)d_in[9];
    const float* eba     = (const float*)d_in[10];
    const float* dW1     = (const float*)d_in[11];
    const float* db1     = (const float*)d_in[12];
    const float* dW2     = (const float*)d_in[13];
    const float* db2     = (const float*)d_in[14];
    const float* dWih    = (const float*)d_in[15];
    const float* dWhh    = (const float*)d_in[16];
    const float* dbih    = (const float*)d_in[17];
    const float* dbhh    = (const float*)d_in[18];
    const float* fcW     = (const float*)d_in[19];
    const float* fcb     = (const float*)d_in[20];
    const float* fcfW    = (const float*)d_in[21];
    const float* fcfb    = (const float*)d_in[22];
    float* out = (float*)d_out;

    float* scr = (float*)d_ws;
    // ---- union region (14,155,776 f) ----
    // encoder view:
    float* t2s    = scr;                        // 4,063,232 f
    float* g0e    = scr + 4063232;              // 4 x 1,048,576 f (split-K slices)
    float* hc_enc = scr + 8257536;              //   524,288 f
    f16*   Af     = (f16*)(scr + 8781824);      //   393,216 h (frag layout, Kg=96)
    // decoder view (encoder scratch dead by then):
    float* V      = scr;                        // 8,126,464 f
    float* gu0    = scr + 8126464;              // 4 x 1,310,720 f
    float* hc_dec = scr + 13369344;             //   524,288 f
    f16*   hdf    = (f16*)(scr + 13893632);     //   524,288 h (frag layout, Kg=128)
    // ---- persistent ----
    f16* fp = (f16*)(scr + 14155776);
    f16* eWhi  = fp;             fp += 1572864;
    f16* eWlo  = fp;             fp += 1572864;
    f16* dWchi = fp;             fp += 2621440;
    f16* dWclo = fp;             fp += 2621440;
    f16* Vwhi  = fp;             fp += 262144;
    f16* Vwlo  = fp;             fp += 262144;
    f16* enchi = fp;             fp += 8126464;
    float* ebcomb = (float*)(((uintptr_t)fp + 15) & ~(uintptr_t)15);
    float* dbias  = ebcomb + 2048;

    hipLaunchKernelGGL(prep_t2s_kernel, dim3(512), dim3(256), 0, stream,
                       inputs, eWih, eWhh, ebih, ebhh, dW1, dWhh, dbih, dbhh,
                       eWd, ebd, eWhi, eWlo, dWchi, dWclo, Vwhi, Vwlo,
                       ebcomb, dbias, t2s);

    const long long gstride = 1048576;
    const long long ustride = 1310720;

    // -------- encoder --------
    for (int t = 0; t < TM1; t++) {
        hipLaunchKernelGGL(enc_step_kernel, dim3(BATCH), dim3(256), 0, stream,
                           inputs, t2s, eWc, ebc, eWa, eba, g0e, gstride, hc_enc,
                           Af, enchi, hc_dec, hdf, t);
        // M=512,N=2048,K=768, KS=4: NT=32, MT=8 -> 1024 blocks (4/CU)
        hipLaunchKernelGGL(gemm_step, dim3(1024), dim3(256), 0, stream,
                           Af, 96, eWhi, eWlo, 768, ebcomb,
                           g0e, 2048, gstride, 768, 1 << 30, 32, 8, 4);
    }
    hipLaunchKernelGGL(enc_step_kernel, dim3(BATCH), dim3(256), 0, stream,
                       inputs, t2s, eWc, ebc, eWa, eba, g0e, gstride, hc_enc,
                       Af, enchi, hc_dec, hdf, TM1);

    // -------- V = enc_out @ dec_W1[:,1024:]^T + b1 --------
    hipLaunchKernelGGL(gemm_v, dim3(992), dim3(256), 0, stream,
                       enchi, 512, Vwhi, Vwlo, 512, db1,
                       V, 512, 512, 4, 248, 2);

    // -------- decoder --------
    for (int t = 0; t < TM1; t++) {
        // M=512,N=2560, KS=4: NT=40, MT=8 -> 1280 blocks
        // n<512: K=1024 ([h|c]); n>=512: K=512 (h only via nsplit)
        hipLaunchKernelGGL(gemm_step, dim3(1280), dim3(256), 0, stream,
                           hdf, 128, dWchi, dWclo, 1024, dbias,
                           gu0, 2560, ustride, 1024, 512, 40, 8, 4);
        hipLaunchKernelGGL(dec_step_kernel, dim3(BATCH), dim3(256), 0, stream,
                           inputs, V, dW2, db2, enchi, fcW, fcb, dWih,
                           gu0, ustride, hc_dec, hdf, fcfW, fcfb, out, t);
    }
}

// Round 9
// 1769.242 us; speedup vs baseline: 1.0870x; 1.0870x over previous
//
#include <hip/hip_runtime.h>
#include <math.h>

#define BATCH 512
#define TM1   31
#define DIMD  256

typedef _Float16 f16;
typedef _Float16 half8 __attribute__((ext_vector_type(8)));
typedef float floatx16 __attribute__((ext_vector_type(16)));

__device__ __forceinline__ float sigmf(float x) { return 1.f / (1.f + __expf(-x)); }

__device__ __forceinline__ float tanh_fast(float x) {
    float ax = fabsf(x);
    float t  = __expf(-2.f * ax);
    float r  = (1.f - t) / (1.f + t);
    return copysignf(r, x);
}

__device__ __forceinline__ void split16(float x, f16* hi, f16* lo) {
    f16 h = (f16)x;
    *hi = h;
    *lo = (f16)(x - (float)h);
}

__device__ __forceinline__ float blockReduceSum256(float v, float* sred) {
#pragma unroll
    for (int m = 32; m > 0; m >>= 1) v += __shfl_xor(v, m);
    __syncthreads();
    if ((threadIdx.x & 63) == 0) sred[threadIdx.x >> 6] = v;
    __syncthreads();
    return sred[0] + sred[1] + sred[2] + sred[3];
}

__device__ __forceinline__ float blockReduceMax256(float v, float* sred) {
#pragma unroll
    for (int m = 32; m > 0; m >>= 1) v = fmaxf(v, __shfl_xor(v, m));
    __syncthreads();
    if ((threadIdx.x & 63) == 0) sred[threadIdx.x >> 6] = v;
    __syncthreads();
    return fmaxf(fmaxf(sred[0], sred[1]), fmaxf(sred[2], sred[3]));
}

// ---------------------------------------------------------------------------
// prep + t2s fused. Weight splits are 8-wide vectorized (float4 x2 loads,
// half8 stores). Block b also computes t2s for batch b.
// ---------------------------------------------------------------------------
__global__ __launch_bounds__(256) void prep_t2s_kernel(
    const float* __restrict__ inputs,
    const float* __restrict__ eWih, const float* __restrict__ eWhh,
    const float* __restrict__ ebih, const float* __restrict__ ebhh,
    const float* __restrict__ dW1,  const float* __restrict__ dWhh,
    const float* __restrict__ dbih, const float* __restrict__ dbhh,
    const float* __restrict__ Wd,   const float* __restrict__ bd,
    f16* __restrict__ eWhi, f16* __restrict__ eWlo,
    f16* __restrict__ dWchi, f16* __restrict__ dWclo,
    f16* __restrict__ Vwhi, f16* __restrict__ Vwlo,
    float* __restrict__ ebcomb, float* __restrict__ dbias,
    float* __restrict__ t2s)
{
    __shared__ float sX[TM1 * DIMD];
    __shared__ float sWd[TM1 * TM1];
    int b = blockIdx.x, tid = threadIdx.x;
    int idx = b * 256 + tid;
    const int stride = 512 * 256;

    // ---- t2s for batch b ----
    for (int i = tid; i < TM1 * DIMD; i += 256) {
        int tt = i >> 8, d = i & 255;
        sX[i] = inputs[((size_t)b * TM1 + tt) * 257 + 1 + d];
    }
    for (int i = tid; i < TM1 * TM1; i += 256) sWd[i] = Wd[i];
    __syncthreads();
    int d = tid;
    for (int s = 0; s < TM1; s++) {
        float acc = bd[s];
        for (int tt = 0; tt < TM1; tt++) acc += sX[tt * DIMD + d] * sWd[s * TM1 + tt];
        t2s[((size_t)b * TM1 + s) * DIMD + d] = acc;
    }

    // ---- eW split: 2048 x 96 groups of 8 ----
    for (int g = idx; g < 2048 * 96; g += stride) {
        int n = g / 96, k0 = (g % 96) * 8;
        const float* src = (k0 < 256) ? (eWih + n * 256 + k0)
                                      : (eWhh + n * 512 + (k0 - 256));
        float4 v0 = *(const float4*)src;
        float4 v1 = *(const float4*)(src + 4);
        float vv[8] = {v0.x, v0.y, v0.z, v0.w, v1.x, v1.y, v1.z, v1.w};
        f16 hi[8], lo[8];
#pragma unroll
        for (int e = 0; e < 8; e++) split16(vv[e], &hi[e], &lo[e]);
        *(half8*)(eWhi + n * 768 + k0) = *(half8*)hi;
        *(half8*)(eWlo + n * 768 + k0) = *(half8*)lo;
    }
    // ---- dWc split: 2560 x 128 groups ----
    for (int g = idx; g < 2560 * 128; g += stride) {
        int n = g >> 7, k0 = (g & 127) * 8;
        float vv[8] = {};
        if (n < 512) {
            const float* src = dW1 + n * 1536 + k0;
            float4 v0 = *(const float4*)src, v1 = *(const float4*)(src + 4);
            vv[0]=v0.x; vv[1]=v0.y; vv[2]=v0.z; vv[3]=v0.w;
            vv[4]=v1.x; vv[5]=v1.y; vv[6]=v1.z; vv[7]=v1.w;
        } else if (k0 < 512) {
            const float* src = dWhh + (n - 512) * 512 + k0;
            float4 v0 = *(const float4*)src, v1 = *(const float4*)(src + 4);
            vv[0]=v0.x; vv[1]=v0.y; vv[2]=v0.z; vv[3]=v0.w;
            vv[4]=v1.x; vv[5]=v1.y; vv[6]=v1.z; vv[7]=v1.w;
        }
        f16 hi[8], lo[8];
#pragma unroll
        for (int e = 0; e < 8; e++) split16(vv[e], &hi[e], &lo[e]);
        *(half8*)(dWchi + n * 1024 + k0) = *(half8*)hi;
        *(half8*)(dWclo + n * 1024 + k0) = *(half8*)lo;
    }
    // ---- Vw split: 512 x 64 groups ----
    for (int g = idx; g < 512 * 64; g += stride) {
        int n = g >> 6, k0 = (g & 63) * 8;
        const float* src = dW1 + n * 1536 + 1024 + k0;
        float4 v0 = *(const float4*)src, v1 = *(const float4*)(src + 4);
        float vv[8] = {v0.x, v0.y, v0.z, v0.w, v1.x, v1.y, v1.z, v1.w};
        f16 hi[8], lo[8];
#pragma unroll
        for (int e = 0; e < 8; e++) split16(vv[e], &hi[e], &lo[e]);
        *(half8*)(Vwhi + n * 512 + k0) = *(half8*)hi;
        *(half8*)(Vwlo + n * 512 + k0) = *(half8*)lo;
    }
    for (int i = idx; i < 2048; i += stride) ebcomb[i] = ebih[i] + ebhh[i];
    for (int i = idx; i < 2560; i += stride)
        dbias[i] = (i < 512) ? 0.f : (dbih[i - 512] + dbhh[i - 512]);
}

// ---------------------------------------------------------------------------
// fp16x2 MFMA GEMM, split-K, f16 output: C_ks[m,n] = sum_{k slice} A[m,k]*
// (Whi+Wlo)[n,k] (+bias if ks==0). R7-validated structure: 64x64 tile,
// 4 waves of 32x32x16, XOR-swizzled LDS, register prefetch.
// grid 1-D: n=bid%NT, m=(bid/NT)%MT, ks=bid/(NT*MT). NT%8==0 -> XCD-pinned
// weight slices. NREP sweeps n-tiles reusing A tile (V-gemm).
// ---------------------------------------------------------------------------
__global__ __launch_bounds__(256) void gemm2f(
    const f16* __restrict__ Ahi, int lda,
    const f16* __restrict__ Whi, const f16* __restrict__ Wlo, int ldw,
    const float* __restrict__ bias, f16* __restrict__ C, int ldc,
    long long Cstride, int K, int nsplit, int NT, int MT, int KS, int NREP)
{
    __shared__ f16 sAh[64 * 64];
    __shared__ f16 sWh[64 * 64];
    __shared__ f16 sWl[64 * 64];
    int tid = threadIdx.x, bid = blockIdx.x;
    int nbase = bid % NT;
    int m0 = ((bid / NT) % MT) * 64;
    int ks = bid / (NT * MT);
    int lane = tid & 63, wid = tid >> 6;
    int wm = wid >> 1, wn = wid & 1;
    int rl = lane & 31, kq = lane >> 5;

    int sr = tid >> 2;
    int g0 = (tid & 3) * 2;
    int s0 = sr * 64 + ((g0 ^ (sr & 7)) * 8);
    int s1 = sr * 64 + (((g0 + 1) ^ (sr & 7)) * 8);
    int arow = (wm * 32 + rl) * 64;
    int wrow = (wn * 32 + rl) * 64;
    int sw = (rl & 7);

    const f16* pAh = Ahi + (size_t)(m0 + sr) * lda + g0 * 8;
    f16* Cp = C + (size_t)ks * Cstride;

    for (int r = 0; r < NREP; ++r) {
        int n0 = (nbase + r * NT) * 64;
        int Kfull = (n0 >= nsplit) ? 512 : K;
        int ksz = Kfull / KS;
        int kbeg = ks * ksz, kend = kbeg + ksz;
        const f16* pWh = Whi + (size_t)(n0 + sr) * ldw + g0 * 8;
        const f16* pWl = Wlo + (size_t)(n0 + sr) * ldw + g0 * 8;

        float4 rAh0 = *(const float4*)(pAh + kbeg);
        float4 rAh1 = *(const float4*)(pAh + kbeg + 8);
        float4 rWh0 = *(const float4*)(pWh + kbeg);
        float4 rWh1 = *(const float4*)(pWh + kbeg + 8);
        float4 rWl0 = *(const float4*)(pWl + kbeg);
        float4 rWl1 = *(const float4*)(pWl + kbeg + 8);

        floatx16 acc = {};

        for (int k0 = kbeg; k0 < kend; k0 += 64) {
            __syncthreads();
            *(float4*)&sAh[s0] = rAh0; *(float4*)&sAh[s1] = rAh1;
            *(float4*)&sWh[s0] = rWh0; *(float4*)&sWh[s1] = rWh1;
            *(float4*)&sWl[s0] = rWl0; *(float4*)&sWl[s1] = rWl1;
            __syncthreads();
            int kn = k0 + 64;
            if (kn < kend) {
                rAh0 = *(const float4*)(pAh + kn); rAh1 = *(const float4*)(pAh + kn + 8);
                rWh0 = *(const float4*)(pWh + kn); rWh1 = *(const float4*)(pWh + kn + 8);
                rWl0 = *(const float4*)(pWl + kn); rWl1 = *(const float4*)(pWl + kn + 8);
            }
#pragma unroll
            for (int kk = 0; kk < 64; kk += 16) {
                int lg = (kk >> 3) + kq;
                int off = ((lg ^ sw) * 8);
                half8 ah = *(const half8*)&sAh[arow + off];
                half8 wh = *(const half8*)&sWh[wrow + off];
                half8 wl = *(const half8*)&sWl[wrow + off];
                acc = __builtin_amdgcn_mfma_f32_32x32x16_f16(ah, wh, acc, 0, 0, 0);
                acc = __builtin_amdgcn_mfma_f32_32x32x16_f16(ah, wl, acc, 0, 0, 0);
            }
        }

        int col = n0 + wn * 32 + rl;
        float bv = (ks == 0) ? bias[col] : 0.f;
#pragma unroll
        for (int rr = 0; rr < 16; ++rr) {
            int row = m0 + wm * 32 + (rr & 3) + 8 * (rr >> 2) + 4 * kq;
            Cp[(size_t)row * ldc + col] = (f16)(acc[rr] + bv);
        }
    }
}

// ---------------------------------------------------------------------------
// Encoder step: 512 blocks, one batch per block. Finalize LSTM t-1 from 2
// f16 g-slices, then attention t. A written plain f16 row-major.
// ---------------------------------------------------------------------------
__global__ __launch_bounds__(256) void enc_step_kernel(
    const float* __restrict__ inputs, const float* __restrict__ t2s,
    const float* __restrict__ Wc, const float* __restrict__ bc,
    const float* __restrict__ Wa, const float* __restrict__ ba,
    const f16* __restrict__ g, long long gstride,
    float* __restrict__ hc,
    f16* __restrict__ Ahi, f16* __restrict__ enchi,
    float* __restrict__ hc_dec, f16* __restrict__ hdhi,
    int t) {
    __shared__ float sh_hc[1024];
    __shared__ float t1s[32];
    __shared__ float sred[4];
    int b = blockIdx.x, tid = threadIdx.x;

    if (t > 0) {
        for (int e = tid; e < 512; e += 256) {
            const f16* gp = g + (size_t)b * 2048 + e;
            float gi = (float)gp[0]    + (float)gp[gstride];
            float gf = (float)gp[512]  + (float)gp[gstride + 512];
            float gg = (float)gp[1024] + (float)gp[gstride + 1024];
            float go = (float)gp[1536] + (float)gp[gstride + 1536];
            float cp = hc[b * 1024 + 512 + e];
            float c2 = sigmf(gf) * cp + sigmf(gi) * tanh_fast(gg);
            float h2 = sigmf(go) * tanh_fast(c2);
            hc[b * 1024 + e] = h2;
            hc[b * 1024 + 512 + e] = c2;
            sh_hc[e] = h2;
            sh_hc[512 + e] = c2;
            enchi[((size_t)b * TM1 + (t - 1)) * 512 + e] = (f16)h2;
        }
    } else {
        for (int j = tid; j < 1024; j += 256) { sh_hc[j] = 0.f; hc[b * 1024 + j] = 0.f; }
    }
    if (t == TM1) {
        for (int j = tid; j < 1024; j += 256) {
            hc_dec[b * 1024 + j] = 0.f;
            hdhi[b * 1024 + j] = (f16)0.f;
        }
        return;
    }
    __syncthreads();

    if (tid < 248) {
        int s = tid >> 3, l8 = tid & 7;
        const float* wrow = Wc + s * 1024;
        float p = 0.f;
        for (int j = l8 * 4; j < 1024; j += 32) {
            float4 w4 = *(const float4*)(wrow + j);
            float4 h4 = *(const float4*)(&sh_hc[j]);
            p += w4.x * h4.x + w4.y * h4.y + w4.z * h4.z + w4.w * h4.w;
        }
        p += __shfl_xor(p, 1); p += __shfl_xor(p, 2); p += __shfl_xor(p, 4);
        if (l8 == 0) t1s[s] = p + bc[s];
    }
    __syncthreads();

    int d = tid;
    float sc = ba[0];
    const float* t2p = t2s + ((size_t)b * TM1) * DIMD + d;
    for (int s = 0; s < TM1; s++) sc += tanh_fast(t1s[s] + t2p[s * DIMD]) * Wa[s];
    float mx = blockReduceMax256(sc, sred);
    float ex = __expf(sc - mx);
    float sm = blockReduceSum256(ex, sred);
    float w = (ex / sm) * inputs[((size_t)b * TM1 + t) * 257 + 1 + d];
    Ahi[b * 768 + d] = (f16)w;
    for (int j = tid; j < 512; j += 256)
        Ahi[b * 768 + 256 + j] = (f16)sh_hc[j];
}

// ---------------------------------------------------------------------------
// Decoder step: attention (f16 V) + ctx + y_tilde + LSTM pointwise from 2
// f16 gu-slices. Last step fuses final FC (ctx never hits global).
// ---------------------------------------------------------------------------
__global__ __launch_bounds__(256) void dec_step_kernel(
    const float* __restrict__ inputs, const f16* __restrict__ V,
    const float* __restrict__ W2, const float* __restrict__ b2,
    const f16* __restrict__ enchi,
    const float* __restrict__ fcW, const float* __restrict__ fcb,
    const float* __restrict__ Wih,
    const f16* __restrict__ gu, long long ustride,
    float* __restrict__ hc, f16* __restrict__ hdhi,
    const float* __restrict__ fcfW, const float* __restrict__ fcfb,
    float* __restrict__ out, int t) {
    __shared__ float su[512];
    __shared__ float sw2[512];
    __shared__ float s_att[TM1];
    __shared__ float sred[4];
    int b = blockIdx.x, tid = threadIdx.x;
    const bool last = (t == TM1 - 1);
    for (int e = tid; e < 512; e += 256) {
        const f16* q = gu + (size_t)b * 2560 + e;
        su[e]  = (float)q[0] + (float)q[ustride];
        sw2[e] = W2[e];
    }
    __syncthreads();
    if (tid < 248) {
        int tp = tid >> 3, l8 = tid & 7;
        const f16* vrow = V + ((size_t)b * TM1 + tp) * 512;
        float p = 0.f;
        for (int j = l8 * 8; j < 512; j += 64) {
            half8 v8 = *(const half8*)(vrow + j);
#pragma unroll
            for (int e = 0; e < 8; e++)
                p += tanh_fast(su[j + e] + (float)v8[e]) * sw2[j + e];
        }
        p += __shfl_xor(p, 1); p += __shfl_xor(p, 2); p += __shfl_xor(p, 4);
        if (l8 == 0) s_att[tp] = p + b2[0];
    }
    __syncthreads();
    if (tid < 64) {
        float v = (tid < TM1) ? s_att[tid] : -3.4e38f;
        float m = v;
#pragma unroll
        for (int k = 32; k > 0; k >>= 1) m = fmaxf(m, __shfl_xor(m, k));
        float e = (tid < TM1) ? __expf(v - m) : 0.f;
        float s = e;
#pragma unroll
        for (int k = 32; k > 0; k >>= 1) s += __shfl_xor(s, k);
        if (tid < TM1) s_att[tid] = e / s;
    }
    __syncthreads();

    float part = 0.f;
    float pctx = 0.f;
#pragma unroll
    for (int r = 0; r < 2; r++) {
        int e = tid + r * 256;
        float cx = 0.f;
        const f16* eh = enchi + (size_t)b * TM1 * 512 + e;
        for (int tp = 0; tp < TM1; tp++)
            cx += s_att[tp] * (float)eh[tp * 512];
        part += cx * fcW[e];
        if (last) pctx += cx * fcfW[512 + e];
    }
    float y = inputs[((size_t)b * TM1 + t) * 257];
    float ysum = blockReduceSum256(part, sred);
    float y_til = ysum + y * fcW[512] + fcb[0];

    float ph = 0.f;
    for (int e = tid; e < 512; e += 256) {
        const f16* q = gu + (size_t)b * 2560 + e;
        float gi = (float)q[512]  + (float)q[ustride + 512]  + y_til * Wih[e];
        float gf = (float)q[1024] + (float)q[ustride + 1024] + y_til * Wih[512 + e];
        float gg = (float)q[1536] + (float)q[ustride + 1536] + y_til * Wih[1024 + e];
        float go = (float)q[2048] + (float)q[ustride + 2048] + y_til * Wih[1536 + e];
        float cp = hc[b * 1024 + 512 + e];
        float c2 = sigmf(gf) * cp + sigmf(gi) * tanh_fast(gg);
        float h2 = sigmf(go) * tanh_fast(c2);
        if (!last) {
            hc[b * 1024 + e] = h2;
            hc[b * 1024 + 512 + e] = c2;
            hdhi[(size_t)b * 1024 + e] = (f16)h2;
            hdhi[(size_t)b * 1024 + 512 + e] = (f16)c2;
        } else {
            ph += h2 * fcfW[e];
        }
    }
    if (last) {
        float s = blockReduceSum256(ph + pctx, sred);
        if (tid == 0) out[b] = s + fcfb[0];
    }
}

extern "C" void kernel_launch(void* const* d_in, const int* in_sizes, int n_in,
                              void* d_out, int out_size, void* d_ws, size_t ws_size,
                              hipStream_t stream) {
    const float* inputs  = (const float*)d_in[0];
    const float* eWih    = (const float*)d_in[1];
    const float* eWhh    = (const float*)d_in[2];
    const float* ebih    = (const float*)d_in[3];
    const float* ebhh    = (const float*)d_in[4];
    const float* eWc     = (const float*)d_in[5];
    const float* ebc     = (const float*)d_in[6];
    const float* eWd     = (const float*)d_in[7];
    const float* ebd     = (const float*)d_in[8];
    const float* eWa     = (const float*)d_in[9];
    const float* eba     = (const float*)d_in[10];
    const float* dW1     = (const float*)d_in[11];
    const float* db1     = (const float*)d_in[12];
    const float* dW2     = (const float*)d_in[13];
    const float* db2     = (const float*)d_in[14];
    const float* dWih    = (const float*)d_in[15];
    const float* dWhh    = (const float*)d_in[16];
    const float* dbih    = (const float*)d_in[17];
    const float* dbhh    = (const float*)d_in[18];
    const float* fcW     = (const float*)d_in[19];
    const float* fcb     = (const float*)d_in[20];
    const float* fcfW    = (const float*)d_in[21];
    const float* fcfb    = (const float*)d_in[22];
    float* out = (float*)d_out;

    float* scr = (float*)d_ws;
    // ---- union A (offset 0, 4,063,232 f): t2s (enc) | V f16 (dec) ----
    float* t2s = scr;                           // 4,063,232 f
    f16*   Vf  = (f16*)scr;                     // 8,126,464 h
    // ---- union B (offset 4,063,232, 1,310,720 f): g-slices | gu-slices ----
    f16* g0e = (f16*)(scr + 4063232);           // 2 x 1,048,576 h
    f16* gu0 = (f16*)(scr + 4063232);           // 2 x 1,310,720 h
    // ---- dedicated ----
    float* hc_enc = scr + 5373952;              //   524,288 f
    f16*   Ahi    = (f16*)(scr + 5898240);      //   393,216 h
    float* hc_dec = scr + 6094848;              //   524,288 f
    f16*   hdhi   = (f16*)(scr + 6619136);      //   524,288 h
    // ---- persistent ----
    f16* fp = (f16*)(scr + 6881280);
    f16* eWhi  = fp;             fp += 1572864;
    f16* eWlo  = fp;             fp += 1572864;
    f16* dWchi = fp;             fp += 2621440;
    f16* dWclo = fp;             fp += 2621440;
    f16* Vwhi  = fp;             fp += 262144;
    f16* Vwlo  = fp;             fp += 262144;
    f16* enchi = fp;             fp += 8126464;
    float* ebcomb = (float*)(((uintptr_t)fp + 15) & ~(uintptr_t)15);
    float* dbias  = ebcomb + 2048;

    hipLaunchKernelGGL(prep_t2s_kernel, dim3(512), dim3(256), 0, stream,
                       inputs, eWih, eWhh, ebih, ebhh, dW1, dWhh, dbih, dbhh,
                       eWd, ebd, eWhi, eWlo, dWchi, dWclo, Vwhi, Vwlo,
                       ebcomb, dbias, t2s);

    const long long gstride = 1048576;   // halves
    const long long ustride = 1310720;   // halves

    // -------- encoder --------
    for (int t = 0; t < TM1; t++) {
        hipLaunchKernelGGL(enc_step_kernel, dim3(BATCH), dim3(256), 0, stream,
                           inputs, t2s, eWc, ebc, eWa, eba, g0e, gstride, hc_enc,
                           Ahi, enchi, hc_dec, hdhi, t);
        // M=512,N=2048,K=768 split-K2: NT=32, MT=8, KS=2 -> 512 blocks
        hipLaunchKernelGGL(gemm2f, dim3(512), dim3(256), 0, stream,
                           Ahi, 768, eWhi, eWlo, 768, ebcomb,
                           g0e, 2048, gstride, 768, 1 << 30, 32, 8, 2, 1);
    }
    hipLaunchKernelGGL(enc_step_kernel, dim3(BATCH), dim3(256), 0, stream,
                       inputs, t2s, eWc, ebc, eWa, eba, g0e, gstride, hc_enc,
                       Ahi, enchi, hc_dec, hdhi, TM1);

    // -------- V = enc_out @ dec_W1[:,1024:]^T + b1 (f16 out) --------
    // M=15872: NT=4, MT=248, KS=1, NREP=2 -> 992 blocks
    hipLaunchKernelGGL(gemm2f, dim3(992), dim3(256), 0, stream,
                       enchi, 512, Vwhi, Vwlo, 512, db1,
                       Vf, 512, 0, 512, 1 << 30, 4, 248, 1, 2);

    // -------- decoder --------
    for (int t = 0; t < TM1; t++) {
        // M=512,N=2560 split-K2: NT=40, MT=8, KS=2 -> 640 blocks
        hipLaunchKernelGGL(gemm2f, dim3(640), dim3(256), 0, stream,
                           hdhi, 1024, dWchi, dWclo, 1024, dbias,
                           gu0, 2560, ustride, 1024, 512, 40, 8, 2, 1);
        hipLaunchKernelGGL(dec_step_kernel, dim3(BATCH), dim3(256), 0, stream,
                           inputs, Vf, dW2, db2, enchi, fcW, fcb, dWih,
                           gu0, ustride, hc_dec, hdhi, fcfW, fcfb, out, t);
    }
}